// Round 2
// 898.382 us; speedup vs baseline: 1.0654x; 1.0654x over previous
//
#include <hip/hip_runtime.h>
#include <hip/hip_bf16.h>
#include <cstdint>
#include <cstddef>

typedef __bf16 bf16;
typedef __bf16 bf16x8 __attribute__((ext_vector_type(8)));
typedef float  f32x4  __attribute__((ext_vector_type(4)));
typedef unsigned int uint32;

#define MFMA16(a, b, c) __builtin_amdgcn_mfma_f32_16x16x32_bf16((a), (b), (c), 0, 0, 0)

static constexpr int Bn = 4, Hn = 8, Sn = 2048, Dn = 128, En = 1024;

// ---------------- conversion kernels ----------------

__global__ void k_cvt_enc(const float* __restrict__ in, bf16* __restrict__ out) {
    int i = blockIdx.x * 256 + threadIdx.x;           // grid covers exactly Bn*Sn*Dn
    out[i] = (bf16)in[i];
}

// W (din x dout) fp32 -> WT (dout x din) bf16 (scaled). din/dout are powers of two.
__global__ void k_cvt_w(const float* __restrict__ w, bf16* __restrict__ wt,
                        int dinLog, int doutLog, float scale) {
    int idx = blockIdx.x * 256 + threadIdx.x;          // grid covers din*dout
    int n = idx >> dinLog;                             // output row (n / e)
    int k = idx & ((1 << dinLog) - 1);                 // contraction index
    wt[idx] = (bf16)(w[(k << doutLog) + n] * scale);
}

__global__ void k_bitmask(const int* __restrict__ m, uint32* __restrict__ bits) {
    int idx = blockIdx.x * 256 + threadIdx.x;          // grid covers Bn*Sn*Sn
    unsigned long long b = __ballot(m[idx] != 0);
    if ((threadIdx.x & 63) == 0) {
        bits[(idx >> 5)]     = (uint32)b;
        bits[(idx >> 5) + 1] = (uint32)(b >> 32);
    }
}

// ---------------- projection GEMM: Q,K (b,h,s,d) and V transposed (b,h,d,s) ----------------

__global__ __launch_bounds__(256) void k_proj(const bf16* __restrict__ encB,
                                              const bf16* __restrict__ wT0,
                                              const bf16* __restrict__ wT1,
                                              const bf16* __restrict__ wT2,
                                              bf16* __restrict__ qb,
                                              bf16* __restrict__ kbuf,
                                              bf16* __restrict__ vt) {
    const int tid = threadIdx.x, w = tid >> 6, lane = tid & 63;
    const int quad = lane >> 4, l15 = lane & 15;
    const int mat = blockIdx.z;              // 0=Q 1=K 2=V
    const int hh  = blockIdx.y;              // e-block == head (128 cols)
    const int e0  = hh * 128;
    const int row0 = blockIdx.x * 64 + w * 16;
    const bf16* wT = (mat == 0) ? wT0 : ((mat == 1) ? wT1 : wT2);

    bf16x8 a[4];
#pragma unroll
    for (int kc = 0; kc < 4; kc++)
        a[kc] = *(const bf16x8*)(encB + (row0 + l15) * Dn + kc * 32 + quad * 8);

    f32x4 acc[8];
#pragma unroll
    for (int nt = 0; nt < 8; nt++) { f32x4 z = {0.f, 0.f, 0.f, 0.f}; acc[nt] = z; }

#pragma unroll
    for (int kc = 0; kc < 4; kc++) {
#pragma unroll
        for (int nt = 0; nt < 8; nt++) {
            bf16x8 b = *(const bf16x8*)(wT + (e0 + nt * 16 + l15) * Dn + kc * 32 + quad * 8);
            acc[nt] = MFMA16(a[kc], b, acc[nt]);
        }
    }

    __shared__ bf16 tile[4 * 16 * 128];   // [64 s-rows][128 d], wave w rows w*16..w*16+15
#pragma unroll
    for (int nt = 0; nt < 8; nt++)
#pragma unroll
        for (int r = 0; r < 4; r++)
            tile[(w * 16 + quad * 4 + r) * 128 + nt * 16 + l15] = (bf16)acc[nt][r];
    __syncthreads();

    if (mat < 2) {
        bf16* outp = (mat == 0) ? qb : kbuf;
#pragma unroll
        for (int it = 0; it < 4; it++) {
            int rr = it * 4 + quad;
            int s  = blockIdx.x * 64 + w * 16 + rr;      // global row 0..8191
            int bb = s >> 11, sl = s & 2047;
            bf16* dst = outp + (((size_t)(bb * Hn + hh) * Sn + sl) * Dn) + l15 * 8;
            *(uint4*)dst = *(const uint4*)(tile + (w * 16 + rr) * 128 + l15 * 8);
        }
    } else {
        // cooperative transposed write: VT[(b,h,d)][s]
        int dr  = tid >> 1;                 // 0..127
        int sc0 = (tid & 1) * 32;           // 0 or 32
        int sg  = blockIdx.x * 64;
        int bb  = sg >> 11, sl0 = sg & 2047;
        unsigned short tmp[32];
#pragma unroll
        for (int i = 0; i < 32; i++) {
            int sl = sc0 + i;
            tmp[i] = *(const unsigned short*)(tile + sl * 128 + dr);
        }
        bf16* dst = vt + ((size_t)(bb * Hn + hh) * Dn + dr) * Sn + sl0 + sc0;
#pragma unroll
        for (int i = 0; i < 4; i++)
            *(uint4*)(dst + i * 8) = *(const uint4*)(tmp + i * 8);
    }
}

// ---------------- fused attention (two-pass exact softmax, writes attn + O) ----------------
// v3: v1 staging structure (known-good) + vectorized attn stores via P restage,
// V stride 88 (odd-dword bank spread), uint2 mask loads, setprio on MFMA clusters.

__global__ __launch_bounds__(256, 2) void k_attn(const bf16* __restrict__ qb,
                                                 const bf16* __restrict__ kbuf,
                                                 const bf16* __restrict__ vt,
                                                 const uint32* __restrict__ bits,
                                                 float* __restrict__ attn,
                                                 bf16* __restrict__ ob) {
    const int tid = threadIdx.x, w = tid >> 6, lane = tid & 63;
    const int quad = lane >> 4, l15 = lane & 15;
    const int qblk = blockIdx.x;          // 0..15
    const int bh   = blockIdx.y;          // 0..31
    const int bb   = bh >> 3, hh = bh & 7;
    const int qw0  = qblk * 128 + w * 32;

    __shared__ __align__(16) char smem[58368];
    bf16*  Klds = (bf16*)smem;                 // [64][136] bf16  (17408 B)
    bf16*  Vlds = (bf16*)(smem + 17408);       // [128][88] bf16  (22528 B)
    float* Plds = (float*)(smem + 39936);      // 4 x [32][36] f32 (18432 B)
    float* Pw   = Plds + w * (32 * 36);

    const bf16* Kbase = kbuf + (size_t)bh * Sn * Dn;
    const bf16* Qbase = qb   + (size_t)bh * Sn * Dn;
    const bf16* Vbase = vt   + (size_t)bh * Dn * Sn;
    const uint32* mbase = bits + (size_t)bb * (Sn * (Sn / 32));
    float* attnbase = attn + (size_t)bh * Sn * Sn;

    bf16x8 aq[2][4];
#pragma unroll
    for (int qs = 0; qs < 2; qs++)
#pragma unroll
        for (int kc = 0; kc < 4; kc++)
            aq[qs][kc] = *(const bf16x8*)(Qbase + (qw0 + qs * 16 + l15) * Dn + kc * 32 + quad * 8);

    float lsum[8];
#pragma unroll
    for (int ri = 0; ri < 8; ri++) lsum[ri] = 0.f;

    // ---------------- pass 1: row sums of exp(score) ----------------
    for (int kb = 0; kb < Sn / 64; kb++) {
        {   // stage K chunk (64 x 128), padded stride 136
            int krow = tid >> 2, c0 = (tid & 3) * 32;
            const bf16* src = Kbase + (size_t)(kb * 64 + krow) * Dn + c0;
            bf16* dst = Klds + krow * 136 + c0;
#pragma unroll
            for (int i = 0; i < 4; i++)
                *(uint4*)(dst + i * 8) = *(const uint4*)(src + i * 8);
        }
        __syncthreads();

        uint32 mw0[8], mw1[8];
#pragma unroll
        for (int ri = 0; ri < 8; ri++) {
            int q = qw0 + (ri >> 2) * 16 + quad * 4 + (ri & 3);
            uint2 m = *(const uint2*)(mbase + (size_t)q * (Sn / 32) + kb * 2);
            mw0[ri] = m.x; mw1[ri] = m.y;
        }

#pragma unroll
        for (int ct = 0; ct < 4; ct++) {
            f32x4 z = {0.f, 0.f, 0.f, 0.f};
            f32x4 sc0 = z, sc1 = z;
            __builtin_amdgcn_s_setprio(1);
#pragma unroll
            for (int kc = 0; kc < 4; kc++) {
                bf16x8 bk = *(const bf16x8*)(Klds + (ct * 16 + l15) * 136 + kc * 32 + quad * 8);
                sc0 = MFMA16(aq[0][kc], bk, sc0);
                sc1 = MFMA16(aq[1][kc], bk, sc1);
            }
            __builtin_amdgcn_s_setprio(0);
            int sh = (ct & 1) * 16 + l15;
            int hi = ct >> 1;
#pragma unroll
            for (int r = 0; r < 4; r++) {
                uint32 m0 = hi ? mw1[r] : mw0[r];
                float v0 = ((m0 >> sh) & 1u) ? sc0[r] : -1e9f;
                lsum[r] += __expf(v0);
                uint32 m1 = hi ? mw1[4 + r] : mw0[4 + r];
                float v1 = ((m1 >> sh) & 1u) ? sc1[r] : -1e9f;
                lsum[4 + r] += __expf(v1);
            }
        }
        __syncthreads();
    }

    float invl[8];
#pragma unroll
    for (int ri = 0; ri < 8; ri++) {
        float t = lsum[ri];
        t += __shfl_xor(t, 1, 64);
        t += __shfl_xor(t, 2, 64);
        t += __shfl_xor(t, 4, 64);
        t += __shfl_xor(t, 8, 64);
        invl[ri] = (t > 0.f) ? (1.0f / t) : 0.0f;
    }

    // ---------------- pass 2: recompute scores, write attn (vectorized), accumulate O ----------------
    f32x4 o[2][8];
#pragma unroll
    for (int qs = 0; qs < 2; qs++)
#pragma unroll
        for (int nt = 0; nt < 8; nt++) { f32x4 z = {0.f, 0.f, 0.f, 0.f}; o[qs][nt] = z; }

    for (int kb = 0; kb < Sn / 64; kb++) {
        {   // stage K
            int krow = tid >> 2, c0 = (tid & 3) * 32;
            const bf16* src = Kbase + (size_t)(kb * 64 + krow) * Dn + c0;
            bf16* dst = Klds + krow * 136 + c0;
#pragma unroll
            for (int i = 0; i < 4; i++)
                *(uint4*)(dst + i * 8) = *(const uint4*)(src + i * 8);
        }
        {   // stage V^T chunk (128 d-rows x 64 kk), padded stride 88
            int dr = tid >> 1, c0 = (tid & 1) * 32;
            const bf16* src = Vbase + (size_t)dr * Sn + kb * 64 + c0;
            bf16* dst = Vlds + dr * 88 + c0;
#pragma unroll
            for (int i = 0; i < 4; i++)
                *(uint4*)(dst + i * 8) = *(const uint4*)(src + i * 8);
        }
        __syncthreads();

        uint32 mw0[8], mw1[8];
#pragma unroll
        for (int ri = 0; ri < 8; ri++) {
            int q = qw0 + (ri >> 2) * 16 + quad * 4 + (ri & 3);
            uint2 m = *(const uint2*)(mbase + (size_t)q * (Sn / 32) + kb * 2);
            mw0[ri] = m.x; mw1[ri] = m.y;
        }

#pragma unroll
        for (int kt = 0; kt < 2; kt++) {
#pragma unroll
            for (int ct2 = 0; ct2 < 2; ct2++) {
                int ct = kt * 2 + ct2;
                f32x4 z = {0.f, 0.f, 0.f, 0.f};
                f32x4 s0 = z, s1 = z;
                __builtin_amdgcn_s_setprio(1);
#pragma unroll
                for (int kc = 0; kc < 4; kc++) {
                    bf16x8 bk = *(const bf16x8*)(Klds + (ct * 16 + l15) * 136 + kc * 32 + quad * 8);
                    s0 = MFMA16(aq[0][kc], bk, s0);
                    s1 = MFMA16(aq[1][kc], bk, s1);
                }
                __builtin_amdgcn_s_setprio(0);
                int sh = (ct & 1) * 16 + l15;
                int hi = ct >> 1;
#pragma unroll
                for (int r = 0; r < 4; r++) {
                    {
                        uint32 m = hi ? mw1[r] : mw0[r];
                        float v = ((m >> sh) & 1u) ? s0[r] : -1e9f;
                        float il = invl[r];
                        float p = __expf(v) * il + ((il == 0.f) ? (1.0f / 2048.0f) : 0.f);
                        Pw[(quad * 4 + r) * 36 + ct2 * 16 + l15] = p;
                    }
                    {
                        uint32 m = hi ? mw1[4 + r] : mw0[4 + r];
                        float v = ((m >> sh) & 1u) ? s1[r] : -1e9f;
                        float il = invl[4 + r];
                        float p = __expf(v) * il + ((il == 0.f) ? (1.0f / 2048.0f) : 0.f);
                        Pw[(16 + quad * 4 + r) * 36 + ct2 * 16 + l15] = p;
                    }
                }
            }
            // P restage -> A-operand layout + vectorized attn global store
            bf16x8 ap[2];
#pragma unroll
            for (int qs = 0; qs < 2; qs++) {
                f32x4 p0 = *(const f32x4*)(Pw + (qs * 16 + l15) * 36 + quad * 8);
                f32x4 p1 = *(const f32x4*)(Pw + (qs * 16 + l15) * 36 + quad * 8 + 4);
                float* gd = attnbase + (size_t)(qw0 + qs * 16 + l15) * Sn + kb * 64 + kt * 32 + quad * 8;
                *(f32x4*)gd = p0;
                *(f32x4*)(gd + 4) = p1;
                bf16x8 t;
                t[0] = (bf16)p0[0]; t[1] = (bf16)p0[1]; t[2] = (bf16)p0[2]; t[3] = (bf16)p0[3];
                t[4] = (bf16)p1[0]; t[5] = (bf16)p1[1]; t[6] = (bf16)p1[2]; t[7] = (bf16)p1[3];
                ap[qs] = t;
            }
            __builtin_amdgcn_s_setprio(1);
#pragma unroll
            for (int nt = 0; nt < 8; nt++) {
                bf16x8 bv = *(const bf16x8*)(Vlds + (nt * 16 + l15) * 88 + kt * 32 + quad * 8);
                o[0][nt] = MFMA16(ap[0], bv, o[0][nt]);
                o[1][nt] = MFMA16(ap[1], bv, o[1][nt]);
            }
            __builtin_amdgcn_s_setprio(0);
        }
        __syncthreads();
    }

    // ---------------- epilogue: O -> (b,s,h*d) bf16 via LDS restage ----------------
    bf16* Olds = (bf16*)smem;             // 4 waves x [32][128], aliases K/V lds (all past barrier)
    bf16* Ow = Olds + w * (32 * 128);
#pragma unroll
    for (int qs = 0; qs < 2; qs++)
#pragma unroll
        for (int nt = 0; nt < 8; nt++)
#pragma unroll
            for (int r = 0; r < 4; r++)
                Ow[(qs * 16 + quad * 4 + r) * 128 + nt * 16 + l15] = (bf16)o[qs][nt][r];
#pragma unroll
    for (int it = 0; it < 8; it++) {
        int rr = it * 4 + quad;
        int s = qblk * 128 + w * 32 + rr;
        bf16* dst = ob + ((size_t)bb * Sn + s) * En + hh * Dn + l15 * 8;
        *(uint4*)dst = *(const uint4*)(Ow + rr * 128 + l15 * 8);
    }
}

// ---------------- final: X = O @ Wo + enc, layernorm, write fp32 ----------------

__global__ __launch_bounds__(256) void k_final(const bf16* __restrict__ ob,
                                               const bf16* __restrict__ woT,
                                               const float* __restrict__ enc,
                                               const float* __restrict__ lnsc,
                                               const float* __restrict__ lnbi,
                                               float* __restrict__ out) {
    const int tid = threadIdx.x, w = tid >> 6, lane = tid & 63;
    const int quad = lane >> 4, l15 = lane & 15;
    const int row0 = blockIdx.x * 64 + w * 16;

    f32x4 acc[8];
#pragma unroll
    for (int nt = 0; nt < 8; nt++) { f32x4 z = {0.f, 0.f, 0.f, 0.f}; acc[nt] = z; }

    for (int kc = 0; kc < 32; kc++) {
        bf16x8 a = *(const bf16x8*)(ob + (size_t)(row0 + l15) * En + kc * 32 + quad * 8);
#pragma unroll
        for (int nt = 0; nt < 8; nt++) {
            bf16x8 b = *(const bf16x8*)(woT + (size_t)(nt * 16 + l15) * En + kc * 32 + quad * 8);
            acc[nt] = MFMA16(a, b, acc[nt]);
        }
    }

#pragma unroll
    for (int r = 0; r < 4; r++) {
        int row = row0 + quad * 4 + r;
        float xv[8];
        float s1 = 0.f, s2 = 0.f;
#pragma unroll
        for (int nt = 0; nt < 8; nt++) {
            float xx = acc[nt][r] + enc[(size_t)row * Dn + nt * 16 + l15];
            xv[nt] = xx;
            s1 += xx;
            s2 += xx * xx;
        }
        s1 += __shfl_xor(s1, 1, 64); s2 += __shfl_xor(s2, 1, 64);
        s1 += __shfl_xor(s1, 2, 64); s2 += __shfl_xor(s2, 2, 64);
        s1 += __shfl_xor(s1, 4, 64); s2 += __shfl_xor(s2, 4, 64);
        s1 += __shfl_xor(s1, 8, 64); s2 += __shfl_xor(s2, 8, 64);
        float mu = s1 * (1.0f / 128.0f);
        float var = s2 * (1.0f / 128.0f) - mu * mu;
        float rs = rsqrtf(var + 1e-6f);
#pragma unroll
        for (int nt = 0; nt < 8; nt++) {
            int col = nt * 16 + l15;
            out[(size_t)row * Dn + col] = (xv[nt] - mu) * rs * lnsc[col] + lnbi[col];
        }
    }
}

// ---------------- host launcher ----------------

extern "C" void kernel_launch(void* const* d_in, const int* in_sizes, int n_in,
                              void* d_out, int out_size, void* d_ws, size_t ws_size,
                              hipStream_t stream) {
    (void)in_sizes; (void)n_in; (void)out_size; (void)ws_size;
    const float* enc  = (const float*)d_in[0];
    const int*   mask = (const int*)d_in[1];
    const float* Wq   = (const float*)d_in[2];
    const float* Wk   = (const float*)d_in[3];
    const float* Wv   = (const float*)d_in[4];
    const float* Wo   = (const float*)d_in[5];
    const float* lnsc = (const float*)d_in[6];
    const float* lnbi = (const float*)d_in[7];

    char* ws = (char*)d_ws;
    bf16*   encB = (bf16*)(ws + 0);             // 2,097,152 B
    bf16*   WqT  = (bf16*)(ws + 2097152);       //   262,144 B
    bf16*   WkT  = (bf16*)(ws + 2359296);
    bf16*   WvT  = (bf16*)(ws + 2621440);
    bf16*   WoT  = (bf16*)(ws + 2883584);
    uint32* bits = (uint32*)(ws + 3145728);     // 2,097,152 B
    bf16*   QB   = (bf16*)(ws + 5242880);       // 16 MiB each
    bf16*   KB   = (bf16*)(ws + 22020096);
    bf16*   VT   = (bf16*)(ws + 38797312);
    bf16*   OB   = (bf16*)(ws + 55574528);      // ends at 72,351,744 B

    float* outp = (float*)d_out;
    float* attn = outp + (size_t)Bn * Sn * Dn;

    k_cvt_enc<<<dim3(4096), dim3(256), 0, stream>>>(enc, encB);
    k_cvt_w<<<dim3(512), dim3(256), 0, stream>>>(Wq, WqT, 7, 10, 0.08838834764831845f);
    k_cvt_w<<<dim3(512), dim3(256), 0, stream>>>(Wk, WkT, 7, 10, 1.0f);
    k_cvt_w<<<dim3(512), dim3(256), 0, stream>>>(Wv, WvT, 7, 10, 1.0f);
    k_cvt_w<<<dim3(512), dim3(256), 0, stream>>>(Wo, WoT, 10, 7, 1.0f);
    k_bitmask<<<dim3(65536), dim3(256), 0, stream>>>(mask, bits);
    k_proj<<<dim3(128, 8, 3), dim3(256), 0, stream>>>(encB, WqT, WkT, WvT, QB, KB, VT);
    k_attn<<<dim3(16, 32), dim3(256), 0, stream>>>(QB, KB, VT, bits, attn, OB);
    k_final<<<dim3(128), dim3(256), 0, stream>>>(OB, WoT, enc, lnsc, lnbi, outp);
}